// Round 16
// baseline (449.206 us; speedup 1.0000x reference)
//
#include <hip/hip_runtime.h>
#include <hip/hip_bf16.h>

#define SQ 2048
#define HH 2048
#define NHEAD 16
#define HD 128
#define QKVW (NHEAD*3*HD)   // 6144

typedef __attribute__((ext_vector_type(8))) short bf16x8;
typedef __attribute__((ext_vector_type(4))) float f32x4;
typedef __attribute__((ext_vector_type(16))) float f32x16;

__device__ inline unsigned short f2bf(float f) {
    union { float f; unsigned u; } x; x.f = f;
    unsigned r = x.u + 0x7FFFu + ((x.u >> 16) & 1u);
    return (unsigned short)(r >> 16);
}

__device__ inline unsigned pack_bf2(float a, float b) {
    return (unsigned)f2bf(a) | ((unsigned)f2bf(b) << 16);
}

__device__ inline float gelu_f(float x) {
    float x3 = x * (1.f + 0.044715f * x * x);
    return 0.5f * x * (1.f + tanhf(0.79788456f * x3));
}

// async global->LDS, 16B per lane. lds must be wave-uniform; g is per-lane.
__device__ inline void gld16(void* lds, const void* g) {
    __builtin_amdgcn_global_load_lds(
        (__attribute__((address_space(1))) void*)(g),
        (__attribute__((address_space(3))) void*)(lds), 16, 0, 0);
}

// ---------------- fp32 -> bf16 convert ----------------
__global__ __launch_bounds__(256) void cvt_kernel(
    const float* __restrict__ in, unsigned short* __restrict__ out, int n4)
{
    int i = blockIdx.x * blockDim.x + threadIdx.x;
    int stride = gridDim.x * blockDim.x;
    for (; i < n4; i += stride) {
        float4 f = ((const float4*)in)[i];
        ushort4 o;
        o.x = f2bf(f.x); o.y = f2bf(f.y); o.z = f2bf(f.z); o.w = f2bf(f.w);
        ((ushort4*)out)[i] = o;
    }
}

// ---------------- LayerNorm: fp32 in -> bf16 out ----------------
__global__ __launch_bounds__(256) void ln_kernel(
    const float* __restrict__ in, const float* __restrict__ g,
    const float* __restrict__ b, unsigned short* __restrict__ out)
{
    int row = blockIdx.x;
    int t = threadIdx.x, lane = t & 63, wid = t >> 6;
    const float4* rp = (const float4*)(in + (size_t)row * HH);
    float4 v0 = rp[t], v1 = rp[t + 256];
    float s  = v0.x + v0.y + v0.z + v0.w + v1.x + v1.y + v1.z + v1.w;
    float ss = v0.x*v0.x + v0.y*v0.y + v0.z*v0.z + v0.w*v0.w
             + v1.x*v1.x + v1.y*v1.y + v1.z*v1.z + v1.w*v1.w;
    #pragma unroll
    for (int o = 32; o; o >>= 1) { s += __shfl_down(s, o); ss += __shfl_down(ss, o); }
    __shared__ float r0[4], r1[4];
    if (lane == 0) { r0[wid] = s; r1[wid] = ss; }
    __syncthreads();
    s  = r0[0] + r0[1] + r0[2] + r0[3];
    ss = r1[0] + r1[1] + r1[2] + r1[3];
    float mu = s * (1.f / HH);
    float var = ss * (1.f / HH) - mu * mu;
    float rs = rsqrtf(var + 1e-5f);
    float4 g0 = ((const float4*)g)[t], g1 = ((const float4*)g)[t + 256];
    float4 b0 = ((const float4*)b)[t], b1 = ((const float4*)b)[t + 256];
    ushort4 o0, o1;
    o0.x = f2bf((v0.x - mu) * rs * g0.x + b0.x);
    o0.y = f2bf((v0.y - mu) * rs * g0.y + b0.y);
    o0.z = f2bf((v0.z - mu) * rs * g0.z + b0.z);
    o0.w = f2bf((v0.w - mu) * rs * g0.w + b0.w);
    o1.x = f2bf((v1.x - mu) * rs * g1.x + b1.x);
    o1.y = f2bf((v1.y - mu) * rs * g1.y + b1.y);
    o1.z = f2bf((v1.z - mu) * rs * g1.z + b1.z);
    o1.w = f2bf((v1.w - mu) * rs * g1.w + b1.w);
    ushort4* op = (ushort4*)(out + (size_t)row * HH);
    op[t] = o0; op[t + 256] = o1;
}

// ---------------- reduce: out = sum(NP partials) + res + bias ----------------
template<int NP>
__global__ __launch_bounds__(256) void reduceN_kernel(
    const float* __restrict__ p0, const float* __restrict__ p1,
    const float* __restrict__ p2, const float* __restrict__ p3,
    const float* __restrict__ res, const float* __restrict__ bias,
    float* __restrict__ out, int n4, int nc4m1)
{
    int i = blockIdx.x * blockDim.x + threadIdx.x;
    int st = gridDim.x * blockDim.x;
    for (; i < n4; i += st) {
        float4 a = ((const float4*)p0)[i];
        float4 b = ((const float4*)p1)[i];
        float4 r = ((const float4*)res)[i];
        float4 bv = ((const float4*)bias)[i & nc4m1];
        float4 o;
        o.x = a.x + b.x + r.x + bv.x;
        o.y = a.y + b.y + r.y + bv.y;
        o.z = a.z + b.z + r.z + bv.z;
        o.w = a.w + b.w + r.w + bv.w;
        if (NP >= 3) {
            float4 c = ((const float4*)p2)[i];
            o.x += c.x; o.y += c.y; o.z += c.z; o.w += c.w;
        }
        if (NP >= 4) {
            float4 d = ((const float4*)p3)[i];
            o.x += d.x; o.y += d.y; o.z += d.z; o.w += d.w;
        }
        ((float4*)out)[i] = o;
    }
}

// ====== 128x128 GEMM, BK=32, bf16 A&B gld16, 4 blocks/CU, depth-2 pipe ======
// C[M,N] = A[M,K]bf16 @ B[N,K]bf16^T. 256 thr = 4 waves (2M x 2N);
// per-wave C 64x64 (4x4 16x16 frags).
// LDS: Asm[3][128][32] (A staged 2 tiles ahead) + Bsm[2][128][32] (1 ahead)
// = 40 KiB -> 4 blocks/CU. Counted vmcnt so loads span barriers:
// iter u: {issue B(u+1)x2, A(u+2)x2; compute u; vmcnt(2) [A(u+2) stays in
// flight; A(u+1),B(u+1) drained after ~1 full compute phase]; s_barrier}.
// Slot ledger: A slot (u+2)%3 last read iter u-1 (1 bar gap); B buf (u+1)%2
// last read iter u-1. Tail clamps re-stage only DEAD slots, in-bounds.

// MODE: 0 = fp32 partial (no bias), 1 = bf16 + bias (+GELU), 2 = QKV splitV
template<int MODE, int GELU_ON>
__global__ __launch_bounds__(256, 4) void gemm128(
    const unsigned short* __restrict__ A, const unsigned short* __restrict__ B,
    const float* __restrict__ bias, void* __restrict__ outp,
    unsigned short* __restrict__ vtb, void* __restrict__ outp_hi,
    int N, int lda, int ldb, int kLen, int Ktot, int CH, int CW)
{
    __shared__ __align__(16) unsigned short Asm[3][128][32];   // 24 KiB
    __shared__ __align__(16) unsigned short Bsm[2][128][32];   // 16 KiB

    int t = threadIdx.x, lane = t & 63, wid = t >> 6;
    int lo = lane & 15, hi = lane >> 4;
    int wr = wid >> 1, wc = wid & 1;

    // 2D chunked XCD swizzle over (R = bz*gy+by, bx); CHxCW rectangle per XCD.
    int id = (blockIdx.z * gridDim.y + blockIdx.y) * gridDim.x + blockIdx.x;
    int xcd = id & 7, local = id >> 3;
    int cgx = gridDim.x / CW;
    int cr = xcd / cgx, cc = xcd - cr * cgx;
    int lr = local / CW, lc = local - lr * CW;
    int R  = cr * CH + lr;
    int bn = cc * CW + lc;
    int bm = R % gridDim.y;
    int bz = R / gridDim.y;
    int m0 = bm * 128, n0 = bn * 128;
    int kstart = bz * kLen;
    int rem = Ktot - kstart;
    int nt = ((rem < kLen) ? rem : kLen) >> 5;   // BK = 32

    // Staging: per thread 2 A-chunks + 2 B-chunks (16B each).
    // thread t -> row (t>>2) and 64+(t>>2), chunk t&3; src chunk XOR (row&3).
    int rS = t >> 2, cS = t & 3;
    int sc0_ = (cS ^ (rS & 3)) << 3;        // (64+rS)&3 == rS&3
    const unsigned short* Ab = A + (size_t)m0 * lda + kstart;
    const unsigned short* Bb = B + (size_t)n0 * ldb + kstart;
    const unsigned short* Asrc0 = Ab + (size_t)rS * lda + sc0_;
    const unsigned short* Asrc1 = Ab + (size_t)(64 + rS) * lda + sc0_;
    const unsigned short* Bsrc0 = Bb + (size_t)rS * ldb + sc0_;
    const unsigned short* Bsrc1 = Bb + (size_t)(64 + rS) * ldb + sc0_;

    // prologue: A(0)->slot0, A(1)->slot1, B(0)->buf0; full drain once.
    gld16(&Asm[0][wid * 16][0], Asrc0);
    gld16(&Asm[0][64 + wid * 16][0], Asrc1);
    gld16(&Bsm[0][wid * 16][0], Bsrc0);
    gld16(&Bsm[0][64 + wid * 16][0], Bsrc1);
    int k1 = (nt > 1) ? 32 : 0;
    gld16(&Asm[1][wid * 16][0], Asrc0 + k1);
    gld16(&Asm[1][64 + wid * 16][0], Asrc1 + k1);
    asm volatile("s_waitcnt vmcnt(0)" ::: "memory");
    __builtin_amdgcn_s_barrier();

    f32x4 acc[4][4] = {};
    int sl0 = 0, sl1 = 1, sl2 = 2;          // A slots: cur, next, stage
    for (int u = 0; u < nt; u++) {
        int bufB = u & 1, nbufB = bufB ^ 1;
        int t1 = ((u + 1 < nt) ? u + 1 : nt - 1) * 32;
        int t2 = ((u + 2 < nt) ? u + 2 : nt - 1) * 32;
        // issue B(u+1) first (must drain this barrier), then A(u+2) (may fly)
        gld16(&Bsm[nbufB][wid * 16][0], Bsrc0 + t1);
        gld16(&Bsm[nbufB][64 + wid * 16][0], Bsrc1 + t1);
        gld16(&Asm[sl2][wid * 16][0], Asrc0 + t2);
        gld16(&Asm[sl2][64 + wid * 16][0], Asrc1 + t2);
        // compute tile u from Asm[sl0], Bsm[bufB]
        __builtin_amdgcn_s_setprio(1);
        {
            const unsigned short (*LA)[32] = Asm[sl0];
            const unsigned short (*LB)[32] = Bsm[bufB];
            bf16x8 af[4], bfr[4];
            #pragma unroll
            for (int i = 0; i < 4; i++) {
                int r = wr * 64 + i * 16 + lo;
                af[i] = *(const bf16x8*)&LA[r][(hi ^ (r & 3)) << 3];
            }
            #pragma unroll
            for (int c = 0; c < 4; c++) {
                int r = wc * 64 + c * 16 + lo;
                bfr[c] = *(const bf16x8*)&LB[r][(hi ^ (r & 3)) << 3];
            }
            #pragma unroll
            for (int i = 0; i < 4; i++)
                #pragma unroll
                for (int c = 0; c < 4; c++)
                    acc[i][c] = __builtin_amdgcn_mfma_f32_16x16x32_bf16(
                        bfr[c], af[i], acc[i][c], 0, 0, 0);
        }
        __builtin_amdgcn_s_setprio(0);
        // drain A(u+1)+B(u+1) (each >= 1 compute phase old); A(u+2) stays.
        asm volatile("s_waitcnt vmcnt(2)" ::: "memory");
        __builtin_amdgcn_s_barrier();
        int tmp = sl0; sl0 = sl1; sl1 = sl2; sl2 = tmp;
    }

    // ---- epilogue ----  acc[i][c][j]: row M = m0+wr*64+i*16+lo,
    //                     col N = n0+wc*64+c*16+hi*4+j (j contiguous in N)
    if (MODE == 0) {
        float* po;
        if (bz == 0)      po = (float*)outp;
        else if (bz == 1) po = (float*)outp + (size_t)SQ * N;
        else if (bz == 2) po = (float*)outp_hi;
        else              po = (float*)vtb;
        #pragma unroll
        for (int i = 0; i < 4; i++) {
            int gr = m0 + wr * 64 + i * 16 + lo;
            #pragma unroll
            for (int c = 0; c < 4; c++) {
                int gc = n0 + wc * 64 + c * 16 + hi * 4;
                *(f32x4*)&po[(size_t)gr * N + gc] = acc[i][c];
            }
        }
    } else if (MODE == 1) {
        unsigned short* op = (unsigned short*)outp;
        #pragma unroll
        for (int i = 0; i < 4; i++) {
            int gr = m0 + wr * 64 + i * 16 + lo;
            #pragma unroll
            for (int c = 0; c < 4; c++) {
                int gc = n0 + wc * 64 + c * 16 + hi * 4;
                float4 bi = *(const float4*)&bias[gc];
                float v0 = acc[i][c][0] + bi.x, v1 = acc[i][c][1] + bi.y;
                float v2 = acc[i][c][2] + bi.z, v3 = acc[i][c][3] + bi.w;
                if (GELU_ON) { v0 = gelu_f(v0); v1 = gelu_f(v1); v2 = gelu_f(v2); v3 = gelu_f(v3); }
                ushort4 o; o.x = f2bf(v0); o.y = f2bf(v1); o.z = f2bf(v2); o.w = f2bf(v3);
                *(ushort4*)&op[(size_t)gr * N + gc] = o;
            }
        }
    } else {
        // QKV: tile (128 cols) is entirely q, k, or v of head n0/384
        unsigned short* op = (unsigned short*)outp;
        int head = n0 / 384;
        int cat = (n0 >> 7) % 3;
        #pragma unroll
        for (int i = 0; i < 4; i++) {
            int gr = m0 + wr * 64 + i * 16 + lo;
            #pragma unroll
            for (int c = 0; c < 4; c++) {
                int gc = n0 + wc * 64 + c * 16 + hi * 4;
                float4 bi = *(const float4*)&bias[gc];
                float v0 = acc[i][c][0] + bi.x, v1 = acc[i][c][1] + bi.y;
                float v2 = acc[i][c][2] + bi.z, v3 = acc[i][c][3] + bi.w;
                if (cat == 2) {             // V columns -> transposed store
                    int d = wc * 64 + c * 16 + hi * 4;
                    unsigned short* vp = vtb + (size_t)(head * HD + d) * SQ + gr;
                    vp[0]      = f2bf(v0);
                    vp[SQ]     = f2bf(v1);
                    vp[2 * SQ] = f2bf(v2);
                    vp[3 * SQ] = f2bf(v3);
                } else {
                    ushort4 o; o.x = f2bf(v0); o.y = f2bf(v1); o.z = f2bf(v2); o.w = f2bf(v3);
                    *(ushort4*)&op[(size_t)gr * N + gc] = o;
                }
            }
        }
    }
}

// ---------------- Flash attention: 32x32 MFMA, causal + alibi ----------------
__global__ __launch_bounds__(128) void attn_kernel(
    const unsigned short* __restrict__ qkvB,  // [S][6144] bf16 (q,k valid)
    const unsigned short* __restrict__ vtb,   // [NH][HD][S] bf16
    unsigned short* __restrict__ ctx)         // [S][2048] bf16
{
    int w = blockIdx.x;
    int lid = (w & 7) * 64 + (w >> 3);
    int n = lid >> 5, qt = lid & 31;
    int t = threadIdx.x, lane = t & 63, wid = t >> 6;
    int l32 = lane & 31, h2 = lane >> 5;
    int q0 = qt * 64, qg = q0 + wid * 32 + l32;

    __shared__ __align__(16) unsigned short Ks[64][128];
    __shared__ __align__(16) unsigned short Vt[128][64];

    bf16x8 qf[8];
    const unsigned short* qp = qkvB + (size_t)qg * QKVW + n * 384 + h2 * 8;
    #pragma unroll
    for (int d8 = 0; d8 < 8; d8++)
        qf[d8] = *(const bf16x8*)(qp + d8 * 16);

    const float slope = exp2f(-0.5f * (float)(n + 1));
    const float inv = 0.08838834764831845f;   // 1/sqrt(128)
    float m = -INFINITY, lsum = 0.f;
    f32x16 ao[4] = {};

    int krow = lane >> 4, kch = lane & 15;
    int vrow = lane >> 3, vch = lane & 7;
    const unsigned short* kb_ = qkvB + n * 384 + 128;
    const unsigned short* vb_ = vtb + (size_t)n * HD * SQ;
    const char* ksb = (const char*)&Ks[0][0];
    const char* vsb = (const char*)&Vt[0][0];

    int nkb = qt + 1;
    for (int kb = 0; kb < nkb; kb++) {
        int k0 = kb * 64;
        __syncthreads();
        #pragma unroll
        for (int s = 0; s < 8; s++) {
            int r = wid * 32 + s * 4 + krow;
            gld16(&Ks[wid * 32 + s * 4][0],
                  kb_ + (size_t)(k0 + r) * QKVW + ((kch ^ (r & 7)) << 3));
            int dd = wid * 64 + s * 8 + vrow;
            gld16(&Vt[wid * 64 + s * 8][0],
                  vb_ + (size_t)dd * SQ + k0 + ((vch ^ (dd & 7)) << 3));
        }
        __syncthreads();

        f32x16 sc0 = {}, sc1 = {};
        #pragma unroll
        for (int d8 = 0; d8 < 8; d8++) {
            int ch = ((d8 * 2 + h2) ^ (l32 & 7)) << 4;
            bf16x8 kf0 = *(const bf16x8*)(ksb + l32 * 256 + ch);
            bf16x8 kf1 = *(const bf16x8*)(ksb + (32 + l32) * 256 + ch);
            sc0 = __builtin_amdgcn_mfma_f32_32x32x16_bf16(kf0, qf[d8], sc0, 0, 0, 0);
            sc1 = __builtin_amdgcn_mfma_f32_32x32x16_bf16(kf1, qf[d8], sc1, 0, 0, 0);
        }

        float tmax = -INFINITY;
        int last = (kb == nkb - 1);
        #pragma unroll
        for (int r = 0; r < 16; r++) {
            int kl = (r & 3) + 8 * (r >> 2) + 4 * h2;
            float s0 = sc0[r] * inv + slope * (float)(k0 + kl);
            float s1 = sc1[r] * inv + slope * (float)(k0 + 32 + kl);
            if (last) {
                if (k0 + kl > qg) s0 = -INFINITY;
                if (k0 + 32 + kl > qg) s1 = -INFINITY;
            }
            sc0[r] = s0; sc1[r] = s1;
            tmax = fmaxf(tmax, fmaxf(s0, s1));
        }
        tmax = fmaxf(tmax, __shfl_xor(tmax, 32));
        if (!__all(tmax <= m + 8.f)) {          // defer-max (T13)
            float mnew = fmaxf(m, tmax);
            float sca = __expf(m - mnew);
            m = mnew;
            lsum *= sca;
            #pragma unroll
            for (int db = 0; db < 4; db++)
                #pragma unroll
                for (int e = 0; e < 16; e++) ao[db][e] *= sca;
        }
        float psum = 0.f;
        #pragma unroll
        for (int r = 0; r < 16; r++) {
            sc0[r] = __expf(sc0[r] - m); psum += sc0[r];
            sc1[r] = __expf(sc1[r] - m); psum += sc1[r];
        }
        psum += __shfl_xor(psum, 32);
        lsum += psum;

        #pragma unroll
        for (int kstep = 0; kstep < 4; kstep++) {
            const int ks1 = kstep & 1;
            float a0, a1, a2, a3, b0, b1, b2, b3;
            if (kstep < 2) {
                a0 = sc0[8*ks1+0]; a1 = sc0[8*ks1+1]; a2 = sc0[8*ks1+2]; a3 = sc0[8*ks1+3];
                b0 = sc0[8*ks1+4]; b1 = sc0[8*ks1+5]; b2 = sc0[8*ks1+6]; b3 = sc0[8*ks1+7];
            } else {
                a0 = sc1[8*ks1+0]; a1 = sc1[8*ks1+1]; a2 = sc1[8*ks1+2]; a3 = sc1[8*ks1+3];
                b0 = sc1[8*ks1+4]; b1 = sc1[8*ks1+5]; b2 = sc1[8*ks1+6]; b3 = sc1[8*ks1+7];
            }
            unsigned ku0 = pack_bf2(h2 ? b0 : a0, h2 ? b1 : a1);
            unsigned ku1 = pack_bf2(h2 ? b2 : a2, h2 ? b3 : a3);
            unsigned su0 = pack_bf2(h2 ? a0 : b0, h2 ? a1 : b1);
            unsigned su1 = pack_bf2(h2 ? a2 : b2, h2 ? a3 : b3);
            unsigned r0 = (unsigned)__shfl_xor((int)su0, 32);
            unsigned r1 = (unsigned)__shfl_xor((int)su1, 32);
            union { int4 i; bf16x8 v; } u;
            u.i.x = h2 ? (int)r0  : (int)ku0;
            u.i.y = h2 ? (int)r1  : (int)ku1;
            u.i.z = h2 ? (int)ku0 : (int)r0;
            u.i.w = h2 ? (int)ku1 : (int)r1;
            bf16x8 pf = u.v;
            int ch = ((kstep * 2 + h2) ^ (l32 & 7)) << 4;
            #pragma unroll
            for (int db = 0; db < 4; db++) {
                bf16x8 vf = *(const bf16x8*)(vsb + (db * 32 + l32) * 128 + ch);
                ao[db] = __builtin_amdgcn_mfma_f32_32x32x16_bf16(vf, pf, ao[db], 0, 0, 0);
            }
        }
    }

    float rl = 1.f / lsum;
    #pragma unroll
    for (int db = 0; db < 4; db++)
        #pragma unroll
        for (int g = 0; g < 4; g++) {
            ushort4 o;
            o.x = f2bf(ao[db][g*4+0] * rl);
            o.y = f2bf(ao[db][g*4+1] * rl);
            o.z = f2bf(ao[db][g*4+2] * rl);
            o.w = f2bf(ao[db][g*4+3] * rl);
            *(ushort4*)(ctx + (size_t)qg * HH + n * HD + db * 32 + g * 8 + h2 * 4) = o;
        }
}

extern "C" void kernel_launch(void* const* d_in, const int* in_sizes, int n_in,
                              void* d_out, int out_size, void* d_ws, size_t ws_size,
                              hipStream_t stream) {
    const float* hs    = (const float*)d_in[0];
    const float* ln1g  = (const float*)d_in[4];
    const float* ln1b  = (const float*)d_in[5];
    const float* qkvw  = (const float*)d_in[6];
    const float* qkvb  = (const float*)d_in[7];
    const float* dw    = (const float*)d_in[8];
    const float* db    = (const float*)d_in[9];
    const float* ln2g  = (const float*)d_in[10];
    const float* ln2b  = (const float*)d_in[11];
    const float* f1w   = (const float*)d_in[12];
    const float* f1b   = (const float*)d_in[13];
    const float* f2w   = (const float*)d_in[14];
    const float* f2b   = (const float*)d_in[15];
    float* out = (float*)d_out;

    char* ws = (char*)d_ws;
    size_t off = 0;
    auto alloc = [&](size_t nbytes) {
        void* p = ws + off; off += (nbytes + 255) & ~(size_t)255; return p;
    };
    unsigned short* xbf  = (unsigned short*)alloc((size_t)SQ * HH * 2);        // [0, 8.39M)
    unsigned short* qkvB = (unsigned short*)alloc((size_t)SQ * QKVW * 2);      // [8.39M, 33.55M)
    unsigned short* vtB  = (unsigned short*)alloc((size_t)NHEAD * HD * SQ * 2);// [33.55M, 41.94M)
    unsigned short* ctx  = (unsigned short*)alloc((size_t)SQ * HH * 2);        // [41.94M, 50.33M)
    float*          attn = (float*)alloc((size_t)SQ * HH * 4);                 // [50.33M, 67.11M)
    unsigned short* y    = (unsigned short*)alloc((size_t)SQ * HH * 2);        // [67.11M, 75.50M)
    unsigned short* hdn  = (unsigned short*)alloc((size_t)SQ * 4 * HH * 2);    // [75.50M, 109.05M)
    unsigned short* wbuf = (unsigned short*)alloc((size_t)4 * HH * HH * 2);    // [109.05M, 142.61M)

    const size_t PQ = (size_t)SQ * HH;      // floats per partial (16.78 MB)
    float* part = (float*)ws;               // partials overlap dead early buffers

    ln_kernel<<<SQ, 256, 0, stream>>>(hs, ln1g, ln1b, xbf);

    // QKV: M=2048,N=6144,K=2048. grid 48x16 = 768 blocks (3/CU); CH=8,CW=12.
    cvt_kernel<<<2048, 256, 0, stream>>>(qkvw, wbuf, QKVW * HH / 4);
    gemm128<2, 0><<<dim3(QKVW / 128, SQ / 128, 1), 256, 0, stream>>>(
        xbf, wbuf, qkvb, qkvB, vtB, nullptr, QKVW, HH, HH, HH, HH, 8, 12);

    attn_kernel<<<512, 128, 0, stream>>>(qkvB, vtB, ctx);

    // dense: split-K x4 (16x16x4 = 1024 blocks, kLen=512); CH=16,CW=8.
    // partials: p0,p1 at ws[0,33.55M) (dead xbf+qkvB); p2,p3 in dead hdn.
    cvt_kernel<<<1024, 256, 0, stream>>>(dw, wbuf, HH * HH / 4);
    gemm128<0, 0><<<dim3(HH / 128, SQ / 128, 4), 256, 0, stream>>>(
        ctx, wbuf, nullptr, part, (unsigned short*)((float*)hdn + PQ), hdn,
        HH, HH, HH, HH / 4, HH, 16, 8);
    reduceN_kernel<4><<<2048, 256, 0, stream>>>(
        part, part + PQ, (float*)hdn, (float*)hdn + PQ, hs, db, attn, SQ * HH / 4, HH / 4 - 1);

    ln_kernel<<<SQ, 256, 0, stream>>>(attn, ln2g, ln2b, y);

    // FC1: M=2048,N=8192,K=2048. grid 64x16 = 1024 blocks (4/CU); CH=8,CW=16.
    cvt_kernel<<<2048, 256, 0, stream>>>(f1w, wbuf, 4 * HH * HH / 4);
    gemm128<1, 1><<<dim3(4 * HH / 128, SQ / 128, 1), 256, 0, stream>>>(
        y, wbuf, f1b, hdn, nullptr, nullptr, 4 * HH, HH, HH, HH, HH, 8, 16);

    // FC2: split-K x3 (16x16x3 = 768 blocks; kLen=2752 -> 2752/2752/2688,
    // Ktot=8192 clamps bz=2). CH=12,CW=8. Partials p0,p1,p2 at ws[0, 50.33M)
    // = dead xbf+qkvB+vtB+ctx, ending exactly at live attn.
    cvt_kernel<<<2048, 256, 0, stream>>>(f2w, wbuf, 4 * HH * HH / 4);
    gemm128<0, 0><<<dim3(HH / 128, SQ / 128, 3), 256, 0, stream>>>(
        hdn, wbuf, nullptr, part, nullptr, part + 2 * PQ,
        HH, 4 * HH, 4 * HH, 2752, 4 * HH, 12, 8);
    reduceN_kernel<3><<<2048, 256, 0, stream>>>(
        part, part + PQ, part + 2 * PQ, nullptr, attn, f2b, out, SQ * HH / 4, HH / 4 - 1);
}

// Round 17
// 444.209 us; speedup vs baseline: 1.0112x; 1.0112x over previous
//
#include <hip/hip_runtime.h>
#include <hip/hip_bf16.h>

#define SQ 2048
#define HH 2048
#define NHEAD 16
#define HD 128
#define QKVW (NHEAD*3*HD)   // 6144

typedef __attribute__((ext_vector_type(8))) short bf16x8;
typedef __attribute__((ext_vector_type(4))) float f32x4;
typedef __attribute__((ext_vector_type(16))) float f32x16;

__device__ inline unsigned short f2bf(float f) {
    union { float f; unsigned u; } x; x.f = f;
    unsigned r = x.u + 0x7FFFu + ((x.u >> 16) & 1u);
    return (unsigned short)(r >> 16);
}

__device__ inline unsigned pack_bf2(float a, float b) {
    return (unsigned)f2bf(a) | ((unsigned)f2bf(b) << 16);
}

__device__ inline float gelu_f(float x) {
    float x3 = x * (1.f + 0.044715f * x * x);
    return 0.5f * x * (1.f + tanhf(0.79788456f * x3));
}

// async global->LDS, 16B per lane. lds must be wave-uniform; g is per-lane.
__device__ inline void gld16(void* lds, const void* g) {
    __builtin_amdgcn_global_load_lds(
        (__attribute__((address_space(1))) void*)(g),
        (__attribute__((address_space(3))) void*)(lds), 16, 0, 0);
}

// ---------------- fp32 -> bf16 convert ----------------
__global__ __launch_bounds__(256) void cvt_kernel(
    const float* __restrict__ in, unsigned short* __restrict__ out, int n4)
{
    int i = blockIdx.x * blockDim.x + threadIdx.x;
    int stride = gridDim.x * blockDim.x;
    for (; i < n4; i += stride) {
        float4 f = ((const float4*)in)[i];
        ushort4 o;
        o.x = f2bf(f.x); o.y = f2bf(f.y); o.z = f2bf(f.z); o.w = f2bf(f.w);
        ((ushort4*)out)[i] = o;
    }
}

// ---------------- LayerNorm: fp32 in -> bf16 out ----------------
__global__ __launch_bounds__(256) void ln_kernel(
    const float* __restrict__ in, const float* __restrict__ g,
    const float* __restrict__ b, unsigned short* __restrict__ out)
{
    int row = blockIdx.x;
    int t = threadIdx.x, lane = t & 63, wid = t >> 6;
    const float4* rp = (const float4*)(in + (size_t)row * HH);
    float4 v0 = rp[t], v1 = rp[t + 256];
    float s  = v0.x + v0.y + v0.z + v0.w + v1.x + v1.y + v1.z + v1.w;
    float ss = v0.x*v0.x + v0.y*v0.y + v0.z*v0.z + v0.w*v0.w
             + v1.x*v1.x + v1.y*v1.y + v1.z*v1.z + v1.w*v1.w;
    #pragma unroll
    for (int o = 32; o; o >>= 1) { s += __shfl_down(s, o); ss += __shfl_down(ss, o); }
    __shared__ float r0[4], r1[4];
    if (lane == 0) { r0[wid] = s; r1[wid] = ss; }
    __syncthreads();
    s  = r0[0] + r0[1] + r0[2] + r0[3];
    ss = r1[0] + r1[1] + r1[2] + r1[3];
    float mu = s * (1.f / HH);
    float var = ss * (1.f / HH) - mu * mu;
    float rs = rsqrtf(var + 1e-5f);
    float4 g0 = ((const float4*)g)[t], g1 = ((const float4*)g)[t + 256];
    float4 b0 = ((const float4*)b)[t], b1 = ((const float4*)b)[t + 256];
    ushort4 o0, o1;
    o0.x = f2bf((v0.x - mu) * rs * g0.x + b0.x);
    o0.y = f2bf((v0.y - mu) * rs * g0.y + b0.y);
    o0.z = f2bf((v0.z - mu) * rs * g0.z + b0.z);
    o0.w = f2bf((v0.w - mu) * rs * g0.w + b0.w);
    o1.x = f2bf((v1.x - mu) * rs * g1.x + b1.x);
    o1.y = f2bf((v1.y - mu) * rs * g1.y + b1.y);
    o1.z = f2bf((v1.z - mu) * rs * g1.z + b1.z);
    o1.w = f2bf((v1.w - mu) * rs * g1.w + b1.w);
    ushort4* op = (ushort4*)(out + (size_t)row * HH);
    op[t] = o0; op[t + 256] = o1;
}

// ---------------- reduce: out = sum(NP partials) + res + bias ----------------
template<int NP>
__global__ __launch_bounds__(256) void reduceN_kernel(
    const float* __restrict__ p0, const float* __restrict__ p1,
    const float* __restrict__ p2, const float* __restrict__ p3,
    const float* __restrict__ res, const float* __restrict__ bias,
    float* __restrict__ out, int n4, int nc4m1)
{
    int i = blockIdx.x * blockDim.x + threadIdx.x;
    int st = gridDim.x * blockDim.x;
    for (; i < n4; i += st) {
        float4 a = ((const float4*)p0)[i];
        float4 b = ((const float4*)p1)[i];
        float4 r = ((const float4*)res)[i];
        float4 bv = ((const float4*)bias)[i & nc4m1];
        float4 o;
        o.x = a.x + b.x + r.x + bv.x;
        o.y = a.y + b.y + r.y + bv.y;
        o.z = a.z + b.z + r.z + bv.z;
        o.w = a.w + b.w + r.w + bv.w;
        if (NP >= 3) {
            float4 c = ((const float4*)p2)[i];
            o.x += c.x; o.y += c.y; o.z += c.z; o.w += c.w;
        }
        if (NP >= 4) {
            float4 d = ((const float4*)p3)[i];
            o.x += d.x; o.y += d.y; o.z += d.z; o.w += d.w;
        }
        ((float4*)out)[i] = o;
    }
}

// ====== 128x128 GEMM, BK=32, bf16 A&B gld16, 4 blocks/CU (R15 + XOR fix) ======
// Row stride 64B -> bank period 2 rows; conflict-free chunk XOR is ((r>>1)&3).
// MODE: 0 = fp32 partial (no bias), 1 = bf16 + bias (+GELU), 2 = QKV splitV
template<int MODE, int GELU_ON>
__global__ __launch_bounds__(256, 4) void gemm128(
    const unsigned short* __restrict__ A, const unsigned short* __restrict__ B,
    const float* __restrict__ bias, void* __restrict__ outp,
    unsigned short* __restrict__ vtb, void* __restrict__ outp_hi,
    int N, int lda, int ldb, int kLen, int Ktot, int CH, int CW)
{
    __shared__ __align__(16) unsigned short Asm[2][128][32];   // 16 KiB
    __shared__ __align__(16) unsigned short Bsm[2][128][32];   // 16 KiB

    int t = threadIdx.x, lane = t & 63, wid = t >> 6;
    int lo = lane & 15, hi = lane >> 4;
    int wr = wid >> 1, wc = wid & 1;

    int id = (blockIdx.z * gridDim.y + blockIdx.y) * gridDim.x + blockIdx.x;
    int xcd = id & 7, local = id >> 3;
    int cgx = gridDim.x / CW;
    int cr = xcd / cgx, cc = xcd - cr * cgx;
    int lr = local / CW, lc = local - lr * CW;
    int R  = cr * CH + lr;
    int bn = cc * CW + lc;
    int bm = R % gridDim.y;
    int bz = R / gridDim.y;
    int m0 = bm * 128, n0 = bn * 128;
    int kstart = bz * kLen;
    int rem = Ktot - kstart;
    int nt = ((rem < kLen) ? rem : kLen) >> 5;   // BK = 32

    // thread t -> rows (t>>2), 64+(t>>2); chunk t&3; src chunk XOR ((r>>1)&3).
    int rS = t >> 2, cS = t & 3;
    int scA0 = (cS ^ ((rS >> 1) & 3)) << 3;
    int scA1 = (cS ^ (((64 + rS) >> 1) & 3)) << 3;
    const unsigned short* Ab = A + (size_t)m0 * lda + kstart;
    const unsigned short* Bb = B + (size_t)n0 * ldb + kstart;
    const unsigned short* Asrc0 = Ab + (size_t)rS * lda + scA0;
    const unsigned short* Asrc1 = Ab + (size_t)(64 + rS) * lda + scA1;
    const unsigned short* Bsrc0 = Bb + (size_t)rS * ldb + scA0;
    const unsigned short* Bsrc1 = Bb + (size_t)(64 + rS) * ldb + scA1;

    gld16(&Asm[0][wid * 16][0], Asrc0);
    gld16(&Asm[0][64 + wid * 16][0], Asrc1);
    gld16(&Bsm[0][wid * 16][0], Bsrc0);
    gld16(&Bsm[0][64 + wid * 16][0], Bsrc1);
    __syncthreads();

    f32x4 acc[4][4] = {};
    for (int u = 0; u < nt; u++) {
        int buf = u & 1, nbuf = buf ^ 1;
        int t1 = ((u + 1 < nt) ? u + 1 : nt - 1) * 32;
        gld16(&Asm[nbuf][wid * 16][0], Asrc0 + t1);
        gld16(&Asm[nbuf][64 + wid * 16][0], Asrc1 + t1);
        gld16(&Bsm[nbuf][wid * 16][0], Bsrc0 + t1);
        gld16(&Bsm[nbuf][64 + wid * 16][0], Bsrc1 + t1);
        __builtin_amdgcn_s_setprio(1);
        {
            bf16x8 af[4], bfr[4];
            #pragma unroll
            for (int i = 0; i < 4; i++) {
                int r = wr * 64 + i * 16 + lo;
                af[i] = *(const bf16x8*)&Asm[buf][r][(hi ^ ((r >> 1) & 3)) << 3];
            }
            #pragma unroll
            for (int c = 0; c < 4; c++) {
                int r = wc * 64 + c * 16 + lo;
                bfr[c] = *(const bf16x8*)&Bsm[buf][r][(hi ^ ((r >> 1) & 3)) << 3];
            }
            #pragma unroll
            for (int i = 0; i < 4; i++)
                #pragma unroll
                for (int c = 0; c < 4; c++)
                    acc[i][c] = __builtin_amdgcn_mfma_f32_16x16x32_bf16(
                        bfr[c], af[i], acc[i][c], 0, 0, 0);
        }
        __builtin_amdgcn_s_setprio(0);
        __syncthreads();
    }

    if (MODE == 0) {
        float* po;
        if (bz == 0)      po = (float*)outp;
        else if (bz == 1) po = (float*)outp + (size_t)SQ * N;
        else if (bz == 2) po = (float*)outp_hi;
        else              po = (float*)vtb;
        #pragma unroll
        for (int i = 0; i < 4; i++) {
            int gr = m0 + wr * 64 + i * 16 + lo;
            #pragma unroll
            for (int c = 0; c < 4; c++) {
                int gc = n0 + wc * 64 + c * 16 + hi * 4;
                *(f32x4*)&po[(size_t)gr * N + gc] = acc[i][c];
            }
        }
    } else if (MODE == 1) {
        unsigned short* op = (unsigned short*)outp;
        #pragma unroll
        for (int i = 0; i < 4; i++) {
            int gr = m0 + wr * 64 + i * 16 + lo;
            #pragma unroll
            for (int c = 0; c < 4; c++) {
                int gc = n0 + wc * 64 + c * 16 + hi * 4;
                float4 bi = *(const float4*)&bias[gc];
                float v0 = acc[i][c][0] + bi.x, v1 = acc[i][c][1] + bi.y;
                float v2 = acc[i][c][2] + bi.z, v3 = acc[i][c][3] + bi.w;
                if (GELU_ON) { v0 = gelu_f(v0); v1 = gelu_f(v1); v2 = gelu_f(v2); v3 = gelu_f(v3); }
                ushort4 o; o.x = f2bf(v0); o.y = f2bf(v1); o.z = f2bf(v2); o.w = f2bf(v3);
                *(ushort4*)&op[(size_t)gr * N + gc] = o;
            }
        }
    } else {
        unsigned short* op = (unsigned short*)outp;
        int head = n0 / 384;
        int cat = (n0 >> 7) % 3;
        #pragma unroll
        for (int i = 0; i < 4; i++) {
            int gr = m0 + wr * 64 + i * 16 + lo;
            #pragma unroll
            for (int c = 0; c < 4; c++) {
                int gc = n0 + wc * 64 + c * 16 + hi * 4;
                float4 bi = *(const float4*)&bias[gc];
                float v0 = acc[i][c][0] + bi.x, v1 = acc[i][c][1] + bi.y;
                float v2 = acc[i][c][2] + bi.z, v3 = acc[i][c][3] + bi.w;
                if (cat == 2) {
                    int d = wc * 64 + c * 16 + hi * 4;
                    unsigned short* vp = vtb + (size_t)(head * HD + d) * SQ + gr;
                    vp[0]      = f2bf(v0);
                    vp[SQ]     = f2bf(v1);
                    vp[2 * SQ] = f2bf(v2);
                    vp[3 * SQ] = f2bf(v3);
                } else {
                    ushort4 o; o.x = f2bf(v0); o.y = f2bf(v1); o.z = f2bf(v2); o.w = f2bf(v3);
                    *(ushort4*)&op[(size_t)gr * N + gc] = o;
                }
            }
        }
    }
}

// ====== 256x256 GEMM, BK=32, 1024 thr = 16 waves (4Mx4N), 64 KiB LDS ======
// Halves staged bytes vs 128^2 (32 KB per iter covers 4x the C-area).
// Each thread stages 1 A-chunk + 1 B-chunk (16B). acc stays 4x4 f32x4/wave.
// MODE: 0 = fp32 partial (split-K x4, p3 in outp_hi), 1 = bf16+bias(+GELU)
template<int MODE, int GELU_ON>
__global__ __launch_bounds__(1024, 4) void gemm1024(
    const unsigned short* __restrict__ A, const unsigned short* __restrict__ B,
    const float* __restrict__ bias, void* __restrict__ outp,
    void* __restrict__ outp_hi,
    int N, int lda, int ldb, int kLen, int Ktot, int CH, int CW)
{
    __shared__ __align__(16) unsigned short Asm[2][256][32];   // 32 KiB
    __shared__ __align__(16) unsigned short Bsm[2][256][32];   // 32 KiB

    int t = threadIdx.x, lane = t & 63, wid = t >> 6;
    int lo = lane & 15, hi = lane >> 4;
    int wr = wid >> 2, wc = wid & 3;

    int id = (blockIdx.z * gridDim.y + blockIdx.y) * gridDim.x + blockIdx.x;
    int xcd = id & 7, local = id >> 3;
    int cgx = gridDim.x / CW;
    int cr = xcd / cgx, cc = xcd - cr * cgx;
    int lr = local / CW, lc = local - lr * CW;
    int R  = cr * CH + lr;
    int bn = cc * CW + lc;
    int bm = R % gridDim.y;
    int bz = R / gridDim.y;
    int m0 = bm * 256, n0 = bn * 256;
    int kstart = bz * kLen;
    int rem = Ktot - kstart;
    int nt = ((rem < kLen) ? rem : kLen) >> 5;   // BK = 32

    // thread t -> row t>>2 (0..255), chunk t&3; src chunk XOR ((r>>1)&3).
    int rS = t >> 2, cS = t & 3;
    int scS = (cS ^ ((rS >> 1) & 3)) << 3;
    const unsigned short* Asrc = A + (size_t)(m0 + rS) * lda + kstart + scS;
    const unsigned short* Bsrc = B + (size_t)(n0 + rS) * ldb + kstart + scS;

    gld16(&Asm[0][wid * 16][0], Asrc);
    gld16(&Bsm[0][wid * 16][0], Bsrc);
    __syncthreads();

    f32x4 acc[4][4] = {};
    for (int u = 0; u < nt; u++) {
        int buf = u & 1, nbuf = buf ^ 1;
        int t1 = ((u + 1 < nt) ? u + 1 : nt - 1) * 32;
        gld16(&Asm[nbuf][wid * 16][0], Asrc + t1);
        gld16(&Bsm[nbuf][wid * 16][0], Bsrc + t1);
        __builtin_amdgcn_s_setprio(1);
        {
            bf16x8 af[4], bfr[4];
            #pragma unroll
            for (int i = 0; i < 4; i++) {
                int r = wr * 64 + i * 16 + lo;
                af[i] = *(const bf16x8*)&Asm[buf][r][(hi ^ ((r >> 1) & 3)) << 3];
            }
            #pragma unroll
            for (int c = 0; c < 4; c++) {
                int r = wc * 64 + c * 16 + lo;
                bfr[c] = *(const bf16x8*)&Bsm[buf][r][(hi ^ ((r >> 1) & 3)) << 3];
            }
            #pragma unroll
            for (int i = 0; i < 4; i++)
                #pragma unroll
                for (int c = 0; c < 4; c++)
                    acc[i][c] = __builtin_amdgcn_mfma_f32_16x16x32_bf16(
                        bfr[c], af[i], acc[i][c], 0, 0, 0);
        }
        __builtin_amdgcn_s_setprio(0);
        __syncthreads();
    }

    if (MODE == 0) {
        float* po = (bz < 3) ? (float*)outp + (size_t)bz * SQ * N
                             : (float*)outp_hi;
        #pragma unroll
        for (int i = 0; i < 4; i++) {
            int gr = m0 + wr * 64 + i * 16 + lo;
            #pragma unroll
            for (int c = 0; c < 4; c++) {
                int gc = n0 + wc * 64 + c * 16 + hi * 4;
                *(f32x4*)&po[(size_t)gr * N + gc] = acc[i][c];
            }
        }
    } else {
        unsigned short* op = (unsigned short*)outp;
        #pragma unroll
        for (int i = 0; i < 4; i++) {
            int gr = m0 + wr * 64 + i * 16 + lo;
            #pragma unroll
            for (int c = 0; c < 4; c++) {
                int gc = n0 + wc * 64 + c * 16 + hi * 4;
                float4 bi = *(const float4*)&bias[gc];
                float v0 = acc[i][c][0] + bi.x, v1 = acc[i][c][1] + bi.y;
                float v2 = acc[i][c][2] + bi.z, v3 = acc[i][c][3] + bi.w;
                if (GELU_ON) { v0 = gelu_f(v0); v1 = gelu_f(v1); v2 = gelu_f(v2); v3 = gelu_f(v3); }
                ushort4 o; o.x = f2bf(v0); o.y = f2bf(v1); o.z = f2bf(v2); o.w = f2bf(v3);
                *(ushort4*)&op[(size_t)gr * N + gc] = o;
            }
        }
    }
}

// ---------------- Flash attention: 32x32 MFMA, causal + alibi ----------------
__global__ __launch_bounds__(128) void attn_kernel(
    const unsigned short* __restrict__ qkvB,  // [S][6144] bf16 (q,k valid)
    const unsigned short* __restrict__ vtb,   // [NH][HD][S] bf16
    unsigned short* __restrict__ ctx)         // [S][2048] bf16
{
    int w = blockIdx.x;
    int lid = (w & 7) * 64 + (w >> 3);
    int n = lid >> 5, qt = lid & 31;
    int t = threadIdx.x, lane = t & 63, wid = t >> 6;
    int l32 = lane & 31, h2 = lane >> 5;
    int q0 = qt * 64, qg = q0 + wid * 32 + l32;

    __shared__ __align__(16) unsigned short Ks[64][128];
    __shared__ __align__(16) unsigned short Vt[128][64];

    bf16x8 qf[8];
    const unsigned short* qp = qkvB + (size_t)qg * QKVW + n * 384 + h2 * 8;
    #pragma unroll
    for (int d8 = 0; d8 < 8; d8++)
        qf[d8] = *(const bf16x8*)(qp + d8 * 16);

    const float slope = exp2f(-0.5f * (float)(n + 1));
    const float inv = 0.08838834764831845f;   // 1/sqrt(128)
    float m = -INFINITY, lsum = 0.f;
    f32x16 ao[4] = {};

    int krow = lane >> 4, kch = lane & 15;
    int vrow = lane >> 3, vch = lane & 7;
    const unsigned short* kb_ = qkvB + n * 384 + 128;
    const unsigned short* vb_ = vtb + (size_t)n * HD * SQ;
    const char* ksb = (const char*)&Ks[0][0];
    const char* vsb = (const char*)&Vt[0][0];

    int nkb = qt + 1;
    for (int kb = 0; kb < nkb; kb++) {
        int k0 = kb * 64;
        __syncthreads();
        #pragma unroll
        for (int s = 0; s < 8; s++) {
            int r = wid * 32 + s * 4 + krow;
            gld16(&Ks[wid * 32 + s * 4][0],
                  kb_ + (size_t)(k0 + r) * QKVW + ((kch ^ (r & 7)) << 3));
            int dd = wid * 64 + s * 8 + vrow;
            gld16(&Vt[wid * 64 + s * 8][0],
                  vb_ + (size_t)dd * SQ + k0 + ((vch ^ (dd & 7)) << 3));
        }
        __syncthreads();

        f32x16 sc0 = {}, sc1 = {};
        #pragma unroll
        for (int d8 = 0; d8 < 8; d8++) {
            int ch = ((d8 * 2 + h2) ^ (l32 & 7)) << 4;
            bf16x8 kf0 = *(const bf16x8*)(ksb + l32 * 256 + ch);
            bf16x8 kf1 = *(const bf16x8*)(ksb + (32 + l32) * 256 + ch);
            sc0 = __builtin_amdgcn_mfma_f32_32x32x16_bf16(kf0, qf[d8], sc0, 0, 0, 0);
            sc1 = __builtin_amdgcn_mfma_f32_32x32x16_bf16(kf1, qf[d8], sc1, 0, 0, 0);
        }

        float tmax = -INFINITY;
        int last = (kb == nkb - 1);
        #pragma unroll
        for (int r = 0; r < 16; r++) {
            int kl = (r & 3) + 8 * (r >> 2) + 4 * h2;
            float s0 = sc0[r] * inv + slope * (float)(k0 + kl);
            float s1 = sc1[r] * inv + slope * (float)(k0 + 32 + kl);
            if (last) {
                if (k0 + kl > qg) s0 = -INFINITY;
                if (k0 + 32 + kl > qg) s1 = -INFINITY;
            }
            sc0[r] = s0; sc1[r] = s1;
            tmax = fmaxf(tmax, fmaxf(s0, s1));
        }
        tmax = fmaxf(tmax, __shfl_xor(tmax, 32));
        if (!__all(tmax <= m + 8.f)) {          // defer-max (T13)
            float mnew = fmaxf(m, tmax);
            float sca = __expf(m - mnew);
            m = mnew;
            lsum *= sca;
            #pragma unroll
            for (int db = 0; db < 4; db++)
                #pragma unroll
                for (int e = 0; e < 16; e++) ao[db][e] *= sca;
        }
        float psum = 0.f;
        #pragma unroll
        for (int r = 0; r < 16; r++) {
            sc0[r] = __expf(sc0[r] - m); psum += sc0[r];
            sc1[r] = __expf(sc1[r] - m); psum += sc1[r];
        }
        psum += __shfl_xor(psum, 32);
        lsum += psum;

        #pragma unroll
        for (int kstep = 0; kstep < 4; kstep++) {
            const int ks1 = kstep & 1;
            float a0, a1, a2, a3, b0, b1, b2, b3;
            if (kstep < 2) {
                a0 = sc0[8*ks1+0]; a1 = sc0[8*ks1+1]; a2 = sc0[8*ks1+2]; a3 = sc0[8*ks1+3];
                b0 = sc0[8*ks1+4]; b1 = sc0[8*ks1+5]; b2 = sc0[8*ks1+6]; b3 = sc0[8*ks1+7];
            } else {
                a0 = sc1[8*ks1+0]; a1 = sc1[8*ks1+1]; a2 = sc1[8*ks1+2]; a3 = sc1[8*ks1+3];
                b0 = sc1[8*ks1+4]; b1 = sc1[8*ks1+5]; b2 = sc1[8*ks1+6]; b3 = sc1[8*ks1+7];
            }
            unsigned ku0 = pack_bf2(h2 ? b0 : a0, h2 ? b1 : a1);
            unsigned ku1 = pack_bf2(h2 ? b2 : a2, h2 ? b3 : a3);
            unsigned su0 = pack_bf2(h2 ? a0 : b0, h2 ? a1 : b1);
            unsigned su1 = pack_bf2(h2 ? a2 : b2, h2 ? a3 : b3);
            unsigned r0 = (unsigned)__shfl_xor((int)su0, 32);
            unsigned r1 = (unsigned)__shfl_xor((int)su1, 32);
            union { int4 i; bf16x8 v; } u;
            u.i.x = h2 ? (int)r0  : (int)ku0;
            u.i.y = h2 ? (int)r1  : (int)ku1;
            u.i.z = h2 ? (int)ku0 : (int)r0;
            u.i.w = h2 ? (int)ku1 : (int)r1;
            bf16x8 pf = u.v;
            int ch = ((kstep * 2 + h2) ^ (l32 & 7)) << 4;
            #pragma unroll
            for (int db = 0; db < 4; db++) {
                bf16x8 vf = *(const bf16x8*)(vsb + (db * 32 + l32) * 128 + ch);
                ao[db] = __builtin_amdgcn_mfma_f32_32x32x16_bf16(vf, pf, ao[db], 0, 0, 0);
            }
        }
    }

    float rl = 1.f / lsum;
    #pragma unroll
    for (int db = 0; db < 4; db++)
        #pragma unroll
        for (int g = 0; g < 4; g++) {
            ushort4 o;
            o.x = f2bf(ao[db][g*4+0] * rl);
            o.y = f2bf(ao[db][g*4+1] * rl);
            o.z = f2bf(ao[db][g*4+2] * rl);
            o.w = f2bf(ao[db][g*4+3] * rl);
            *(ushort4*)(ctx + (size_t)qg * HH + n * HD + db * 32 + g * 8 + h2 * 4) = o;
        }
}

extern "C" void kernel_launch(void* const* d_in, const int* in_sizes, int n_in,
                              void* d_out, int out_size, void* d_ws, size_t ws_size,
                              hipStream_t stream) {
    const float* hs    = (const float*)d_in[0];
    const float* ln1g  = (const float*)d_in[4];
    const float* ln1b  = (const float*)d_in[5];
    const float* qkvw  = (const float*)d_in[6];
    const float* qkvb  = (const float*)d_in[7];
    const float* dw    = (const float*)d_in[8];
    const float* db    = (const float*)d_in[9];
    const float* ln2g  = (const float*)d_in[10];
    const float* ln2b  = (const float*)d_in[11];
    const float* f1w   = (const float*)d_in[12];
    const float* f1b   = (const float*)d_in[13];
    const float* f2w   = (const float*)d_in[14];
    const float* f2b   = (const float*)d_in[15];
    float* out = (float*)d_out;

    char* ws = (char*)d_ws;
    size_t off = 0;
    auto alloc = [&](size_t nbytes) {
        void* p = ws + off; off += (nbytes + 255) & ~(size_t)255; return p;
    };
    unsigned short* xbf  = (unsigned short*)alloc((size_t)SQ * HH * 2);        // [0, 8.39M)
    unsigned short* qkvB = (unsigned short*)alloc((size_t)SQ * QKVW * 2);      // [8.39M, 33.55M)
    unsigned short* vtB  = (unsigned short*)alloc((size_t)NHEAD * HD * SQ * 2);// [33.55M, 41.94M)
    unsigned short* ctx  = (unsigned short*)alloc((size_t)SQ * HH * 2);        // [41.94M, 50.33M)
    float*          attn = (float*)alloc((size_t)SQ * HH * 4);                 // [50.33M, 67.11M)
    unsigned short* y    = (unsigned short*)alloc((size_t)SQ * HH * 2);        // [67.11M, 75.50M)
    unsigned short* hdn  = (unsigned short*)alloc((size_t)SQ * 4 * HH * 2);    // [75.50M, 109.05M)
    unsigned short* wbuf = (unsigned short*)alloc((size_t)4 * HH * HH * 2);    // [109.05M, 142.61M)

    const size_t PQ = (size_t)SQ * HH;      // floats per partial (16.78 MB)
    float* part = (float*)ws;               // partials overlap dead early buffers

    ln_kernel<<<SQ, 256, 0, stream>>>(hs, ln1g, ln1b, xbf);

    // QKV: M=2048,N=6144,K=2048. grid 48x16 = 768 blocks; CH=8,CW=12.
    cvt_kernel<<<2048, 256, 0, stream>>>(qkvw, wbuf, QKVW * HH / 4);
    gemm128<2, 0><<<dim3(QKVW / 128, SQ / 128, 1), 256, 0, stream>>>(
        xbf, wbuf, qkvb, qkvB, vtB, nullptr, QKVW, HH, HH, HH, HH, 8, 12);

    attn_kernel<<<512, 128, 0, stream>>>(qkvB, vtB, ctx);

    // dense: split-K x4 (16x16x4 = 1024 blocks, kLen=512); CH=16,CW=8.
    // partials: p0,p1 at ws[0,33.55M); p2,p3 in dead hdn.
    cvt_kernel<<<1024, 256, 0, stream>>>(dw, wbuf, HH * HH / 4);
    gemm128<0, 0><<<dim3(HH / 128, SQ / 128, 4), 256, 0, stream>>>(
        ctx, wbuf, nullptr, part, (unsigned short*)((float*)hdn + PQ), hdn,
        HH, HH, HH, HH / 4, HH, 16, 8);
    reduceN_kernel<4><<<2048, 256, 0, stream>>>(
        part, part + PQ, (float*)hdn, (float*)hdn + PQ, hs, db, attn, SQ * HH / 4, HH / 4 - 1);

    ln_kernel<<<SQ, 256, 0, stream>>>(attn, ln2g, ln2b, y);

    // FC1: 256^2 tile. grid 32x8 = 256 blocks; CH=4,CW=8 (cgx=4).
    cvt_kernel<<<2048, 256, 0, stream>>>(f1w, wbuf, 4 * HH * HH / 4);
    gemm1024<1, 1><<<dim3(4 * HH / 256, SQ / 256, 1), 1024, 0, stream>>>(
        y, wbuf, f1b, hdn, nullptr, 4 * HH, HH, HH, HH, HH, 4, 8);

    // FC2: 256^2 tile, split-K x4 (8x8x4 = 256 blocks, kLen=2048); CH=8,CW=4.
    // partials p0,p1,p2 at ws[0,50.33M) (dead xbf+qkvB+vtB+ctx); p3 = out.
    cvt_kernel<<<2048, 256, 0, stream>>>(f2w, wbuf, 4 * HH * HH / 4);
    gemm1024<0, 0><<<dim3(HH / 256, SQ / 256, 4), 1024, 0, stream>>>(
        hdn, wbuf, nullptr, part, out, HH, 4 * HH, 4 * HH, HH, 4 * HH, 8, 4);
    reduceN_kernel<4><<<2048, 256, 0, stream>>>(
        part, part + PQ, part + 2 * PQ, out, attn, f2b, out, SQ * HH / 4, HH / 4 - 1);
}

// Round 18
// 415.653 us; speedup vs baseline: 1.0807x; 1.0687x over previous
//
#include <hip/hip_runtime.h>
#include <hip/hip_bf16.h>

#define SQ 2048
#define HH 2048
#define NHEAD 16
#define HD 128
#define QKVW (NHEAD*3*HD)   // 6144

typedef __attribute__((ext_vector_type(8))) short bf16x8;
typedef __attribute__((ext_vector_type(4))) float f32x4;
typedef __attribute__((ext_vector_type(16))) float f32x16;

__device__ inline unsigned short f2bf(float f) {
    union { float f; unsigned u; } x; x.f = f;
    unsigned r = x.u + 0x7FFFu + ((x.u >> 16) & 1u);
    return (unsigned short)(r >> 16);
}

__device__ inline unsigned pack_bf2(float a, float b) {
    return (unsigned)f2bf(a) | ((unsigned)f2bf(b) << 16);
}

__device__ inline float gelu_f(float x) {
    float x3 = x * (1.f + 0.044715f * x * x);
    return 0.5f * x * (1.f + tanhf(0.79788456f * x3));
}

// async global->LDS, 16B per lane. lds must be wave-uniform; g is per-lane.
__device__ inline void gld16(void* lds, const void* g) {
    __builtin_amdgcn_global_load_lds(
        (__attribute__((address_space(1))) void*)(g),
        (__attribute__((address_space(3))) void*)(lds), 16, 0, 0);
}

// ---------------- fp32 -> bf16 convert ----------------
__global__ __launch_bounds__(256) void cvt_kernel(
    const float* __restrict__ in, unsigned short* __restrict__ out, int n4)
{
    int i = blockIdx.x * blockDim.x + threadIdx.x;
    int stride = gridDim.x * blockDim.x;
    for (; i < n4; i += stride) {
        float4 f = ((const float4*)in)[i];
        ushort4 o;
        o.x = f2bf(f.x); o.y = f2bf(f.y); o.z = f2bf(f.z); o.w = f2bf(f.w);
        ((ushort4*)out)[i] = o;
    }
}

// ---------------- LayerNorm: fp32 in -> bf16 out ----------------
__global__ __launch_bounds__(256) void ln_kernel(
    const float* __restrict__ in, const float* __restrict__ g,
    const float* __restrict__ b, unsigned short* __restrict__ out)
{
    int row = blockIdx.x;
    int t = threadIdx.x, lane = t & 63, wid = t >> 6;
    const float4* rp = (const float4*)(in + (size_t)row * HH);
    float4 v0 = rp[t], v1 = rp[t + 256];
    float s  = v0.x + v0.y + v0.z + v0.w + v1.x + v1.y + v1.z + v1.w;
    float ss = v0.x*v0.x + v0.y*v0.y + v0.z*v0.z + v0.w*v0.w
             + v1.x*v1.x + v1.y*v1.y + v1.z*v1.z + v1.w*v1.w;
    #pragma unroll
    for (int o = 32; o; o >>= 1) { s += __shfl_down(s, o); ss += __shfl_down(ss, o); }
    __shared__ float r0[4], r1[4];
    if (lane == 0) { r0[wid] = s; r1[wid] = ss; }
    __syncthreads();
    s  = r0[0] + r0[1] + r0[2] + r0[3];
    ss = r1[0] + r1[1] + r1[2] + r1[3];
    float mu = s * (1.f / HH);
    float var = ss * (1.f / HH) - mu * mu;
    float rs = rsqrtf(var + 1e-5f);
    float4 g0 = ((const float4*)g)[t], g1 = ((const float4*)g)[t + 256];
    float4 b0 = ((const float4*)b)[t], b1 = ((const float4*)b)[t + 256];
    ushort4 o0, o1;
    o0.x = f2bf((v0.x - mu) * rs * g0.x + b0.x);
    o0.y = f2bf((v0.y - mu) * rs * g0.y + b0.y);
    o0.z = f2bf((v0.z - mu) * rs * g0.z + b0.z);
    o0.w = f2bf((v0.w - mu) * rs * g0.w + b0.w);
    o1.x = f2bf((v1.x - mu) * rs * g1.x + b1.x);
    o1.y = f2bf((v1.y - mu) * rs * g1.y + b1.y);
    o1.z = f2bf((v1.z - mu) * rs * g1.z + b1.z);
    o1.w = f2bf((v1.w - mu) * rs * g1.w + b1.w);
    ushort4* op = (ushort4*)(out + (size_t)row * HH);
    op[t] = o0; op[t + 256] = o1;
}

// ---------------- reduce: out = sum(NP partials) + res + bias ----------------
template<int NP>
__global__ __launch_bounds__(256) void reduceN_kernel(
    const float* __restrict__ p0, const float* __restrict__ p1,
    const float* __restrict__ p2, const float* __restrict__ p3,
    const float* __restrict__ res, const float* __restrict__ bias,
    float* __restrict__ out, int n4, int nc4m1)
{
    int i = blockIdx.x * blockDim.x + threadIdx.x;
    int st = gridDim.x * blockDim.x;
    for (; i < n4; i += st) {
        float4 a = ((const float4*)p0)[i];
        float4 b = ((const float4*)p1)[i];
        float4 r = ((const float4*)res)[i];
        float4 bv = ((const float4*)bias)[i & nc4m1];
        float4 o;
        o.x = a.x + b.x + r.x + bv.x;
        o.y = a.y + b.y + r.y + bv.y;
        o.z = a.z + b.z + r.z + bv.z;
        o.w = a.w + b.w + r.w + bv.w;
        if (NP >= 3) {
            float4 c = ((const float4*)p2)[i];
            o.x += c.x; o.y += c.y; o.z += c.z; o.w += c.w;
        }
        if (NP >= 4) {
            float4 d = ((const float4*)p3)[i];
            o.x += d.x; o.y += d.y; o.z += d.z; o.w += d.w;
        }
        ((float4*)out)[i] = o;
    }
}

// ====== 256x256 GEMM, BK=64, 1024 thr = 16 waves (4Mx4N), 128 KiB LDS ======
// Chain model: wall = nt x T_chain; BK=64 halves nt vs BK=32.
// LDS rows 128B: bank depends only on 16B-chunk index -> XOR c^(r&7) makes
// frag reads 2-way (free). Staging: thread t -> rows (t>>3), 128+(t>>3),
// chunk t&7, src pre-XOR'd; per wave each gld16 covers 8 rows linearly.
// Loop: {stage tile u+1 -> buf^1 (2A+2B gld16); compute u (32 MFMA); sync}.
// MODE: 0 = fp32 partial (4-way pointer select), 1 = bf16+bias(+GELU),
//       2 = QKV splitV (per-column q/k/v routing)
template<int MODE, int GELU_ON>
__global__ __launch_bounds__(1024, 4) void gemm1024(
    const unsigned short* __restrict__ A, const unsigned short* __restrict__ B,
    const float* __restrict__ bias, void* __restrict__ outp,
    unsigned short* __restrict__ vtb, void* __restrict__ outp_hi,
    void* __restrict__ outp_hi2,
    int N, int lda, int ldb, int kLen, int Ktot, int CH, int CW)
{
    __shared__ __align__(16) unsigned short Asm[2][256][64];   // 64 KiB
    __shared__ __align__(16) unsigned short Bsm[2][256][64];   // 64 KiB

    int t = threadIdx.x, lane = t & 63, wid = t >> 6;
    int lo = lane & 15, hi = lane >> 4;
    int wr = wid >> 2, wc = wid & 3;

    // 2D chunked XCD swizzle over (R = bz*gy+by, bx); CHxCW rectangle per XCD.
    int id = (blockIdx.z * gridDim.y + blockIdx.y) * gridDim.x + blockIdx.x;
    int xcd = id & 7, local = id >> 3;
    int cgx = gridDim.x / CW;
    int cr = xcd / cgx, cc = xcd - cr * cgx;
    int lr = local / CW, lc = local - lr * CW;
    int R  = cr * CH + lr;
    int bn = cc * CW + lc;
    int bm = R % gridDim.y;
    int bz = R / gridDim.y;
    int m0 = bm * 256, n0 = bn * 256;
    int kstart = bz * kLen;
    int rem = Ktot - kstart;
    int nt = ((rem < kLen) ? rem : kLen) >> 6;   // BK = 64

    // staging: thread t -> rows rS, 128+rS; chunk cS; src chunk ^ (rS&7)
    int rS = t >> 3, cS = t & 7;
    int scS = (cS ^ (rS & 7)) << 3;             // (128+rS)&7 == rS&7
    const unsigned short* Asrc0 = A + (size_t)(m0 + rS) * lda + kstart + scS;
    const unsigned short* Asrc1 = A + (size_t)(m0 + 128 + rS) * lda + kstart + scS;
    const unsigned short* Bsrc0 = B + (size_t)(n0 + rS) * ldb + kstart + scS;
    const unsigned short* Bsrc1 = B + (size_t)(n0 + 128 + rS) * ldb + kstart + scS;

    // prologue: tile 0 -> buf 0
    gld16(&Asm[0][wid * 8][0], Asrc0);
    gld16(&Asm[0][128 + wid * 8][0], Asrc1);
    gld16(&Bsm[0][wid * 8][0], Bsrc0);
    gld16(&Bsm[0][128 + wid * 8][0], Bsrc1);
    __syncthreads();

    f32x4 acc[4][4] = {};
    for (int u = 0; u < nt; u++) {
        int buf = u & 1, nbuf = buf ^ 1;
        int t1 = ((u + 1 < nt) ? u + 1 : nt - 1) * 64;
        gld16(&Asm[nbuf][wid * 8][0], Asrc0 + t1);
        gld16(&Asm[nbuf][128 + wid * 8][0], Asrc1 + t1);
        gld16(&Bsm[nbuf][wid * 8][0], Bsrc0 + t1);
        gld16(&Bsm[nbuf][128 + wid * 8][0], Bsrc1 + t1);
        __builtin_amdgcn_s_setprio(1);
        #pragma unroll
        for (int ks = 0; ks < 2; ks++) {
            int g = ks * 4 + hi;
            bf16x8 af[4], bfr[4];
            #pragma unroll
            for (int i = 0; i < 4; i++) {
                int r = wr * 64 + i * 16 + lo;
                af[i] = *(const bf16x8*)&Asm[buf][r][(g ^ (r & 7)) << 3];
            }
            #pragma unroll
            for (int c = 0; c < 4; c++) {
                int r = wc * 64 + c * 16 + lo;
                bfr[c] = *(const bf16x8*)&Bsm[buf][r][(g ^ (r & 7)) << 3];
            }
            #pragma unroll
            for (int i = 0; i < 4; i++)
                #pragma unroll
                for (int c = 0; c < 4; c++)
                    acc[i][c] = __builtin_amdgcn_mfma_f32_16x16x32_bf16(
                        bfr[c], af[i], acc[i][c], 0, 0, 0);
        }
        __builtin_amdgcn_s_setprio(0);
        __syncthreads();
    }

    // ---- epilogue ----  acc[i][c][j]: row M = m0+wr*64+i*16+lo,
    //                     col N = n0+wc*64+c*16+hi*4+j (j contiguous in N)
    if (MODE == 0) {
        float* po;
        if (bz == 0)      po = (float*)outp;
        else if (bz == 1) po = (float*)outp + (size_t)SQ * N;
        else if (bz == 2) po = (float*)outp_hi;
        else              po = (float*)outp_hi2;
        #pragma unroll
        for (int i = 0; i < 4; i++) {
            int gr = m0 + wr * 64 + i * 16 + lo;
            #pragma unroll
            for (int c = 0; c < 4; c++) {
                int gc = n0 + wc * 64 + c * 16 + hi * 4;
                *(f32x4*)&po[(size_t)gr * N + gc] = acc[i][c];
            }
        }
    } else if (MODE == 1) {
        unsigned short* op = (unsigned short*)outp;
        #pragma unroll
        for (int i = 0; i < 4; i++) {
            int gr = m0 + wr * 64 + i * 16 + lo;
            #pragma unroll
            for (int c = 0; c < 4; c++) {
                int gc = n0 + wc * 64 + c * 16 + hi * 4;
                float4 bi = *(const float4*)&bias[gc];
                float v0 = acc[i][c][0] + bi.x, v1 = acc[i][c][1] + bi.y;
                float v2 = acc[i][c][2] + bi.z, v3 = acc[i][c][3] + bi.w;
                if (GELU_ON) { v0 = gelu_f(v0); v1 = gelu_f(v1); v2 = gelu_f(v2); v3 = gelu_f(v3); }
                ushort4 o; o.x = f2bf(v0); o.y = f2bf(v1); o.z = f2bf(v2); o.w = f2bf(v3);
                *(ushort4*)&op[(size_t)gr * N + gc] = o;
            }
        }
    } else {
        // QKV: 256-wide tile crosses q/k/v boundaries; route per column group.
        unsigned short* op = (unsigned short*)outp;
        #pragma unroll
        for (int i = 0; i < 4; i++) {
            int gr = m0 + wr * 64 + i * 16 + lo;
            #pragma unroll
            for (int c = 0; c < 4; c++) {
                int gc = n0 + wc * 64 + c * 16 + hi * 4;
                int head = gc / 384;
                int within = gc - head * 384;
                float4 bi = *(const float4*)&bias[gc];
                float v0 = acc[i][c][0] + bi.x, v1 = acc[i][c][1] + bi.y;
                float v2 = acc[i][c][2] + bi.z, v3 = acc[i][c][3] + bi.w;
                if (within >= 256) {        // V columns -> transposed store
                    int d = within - 256;
                    unsigned short* vp = vtb + (size_t)(head * HD + d) * SQ + gr;
                    vp[0]      = f2bf(v0);
                    vp[SQ]     = f2bf(v1);
                    vp[2 * SQ] = f2bf(v2);
                    vp[3 * SQ] = f2bf(v3);
                } else {
                    ushort4 o; o.x = f2bf(v0); o.y = f2bf(v1); o.z = f2bf(v2); o.w = f2bf(v3);
                    *(ushort4*)&op[(size_t)gr * N + gc] = o;
                }
            }
        }
    }
}

// ---------------- Flash attention: 32x32 MFMA, causal + alibi ----------------
__global__ __launch_bounds__(128) void attn_kernel(
    const unsigned short* __restrict__ qkvB,  // [S][6144] bf16 (q,k valid)
    const unsigned short* __restrict__ vtb,   // [NH][HD][S] bf16
    unsigned short* __restrict__ ctx)         // [S][2048] bf16
{
    int w = blockIdx.x;
    int lid = (w & 7) * 64 + (w >> 3);
    int n = lid >> 5, qt = lid & 31;
    int t = threadIdx.x, lane = t & 63, wid = t >> 6;
    int l32 = lane & 31, h2 = lane >> 5;
    int q0 = qt * 64, qg = q0 + wid * 32 + l32;

    __shared__ __align__(16) unsigned short Ks[64][128];
    __shared__ __align__(16) unsigned short Vt[128][64];

    bf16x8 qf[8];
    const unsigned short* qp = qkvB + (size_t)qg * QKVW + n * 384 + h2 * 8;
    #pragma unroll
    for (int d8 = 0; d8 < 8; d8++)
        qf[d8] = *(const bf16x8*)(qp + d8 * 16);

    const float slope = exp2f(-0.5f * (float)(n + 1));
    const float inv = 0.08838834764831845f;   // 1/sqrt(128)
    float m = -INFINITY, lsum = 0.f;
    f32x16 ao[4] = {};

    int krow = lane >> 4, kch = lane & 15;
    int vrow = lane >> 3, vch = lane & 7;
    const unsigned short* kb_ = qkvB + n * 384 + 128;
    const unsigned short* vb_ = vtb + (size_t)n * HD * SQ;
    const char* ksb = (const char*)&Ks[0][0];
    const char* vsb = (const char*)&Vt[0][0];

    int nkb = qt + 1;
    for (int kb = 0; kb < nkb; kb++) {
        int k0 = kb * 64;
        __syncthreads();
        #pragma unroll
        for (int s = 0; s < 8; s++) {
            int r = wid * 32 + s * 4 + krow;
            gld16(&Ks[wid * 32 + s * 4][0],
                  kb_ + (size_t)(k0 + r) * QKVW + ((kch ^ (r & 7)) << 3));
            int dd = wid * 64 + s * 8 + vrow;
            gld16(&Vt[wid * 64 + s * 8][0],
                  vb_ + (size_t)dd * SQ + k0 + ((vch ^ (dd & 7)) << 3));
        }
        __syncthreads();

        f32x16 sc0 = {}, sc1 = {};
        #pragma unroll
        for (int d8 = 0; d8 < 8; d8++) {
            int ch = ((d8 * 2 + h2) ^ (l32 & 7)) << 4;
            bf16x8 kf0 = *(const bf16x8*)(ksb + l32 * 256 + ch);
            bf16x8 kf1 = *(const bf16x8*)(ksb + (32 + l32) * 256 + ch);
            sc0 = __builtin_amdgcn_mfma_f32_32x32x16_bf16(kf0, qf[d8], sc0, 0, 0, 0);
            sc1 = __builtin_amdgcn_mfma_f32_32x32x16_bf16(kf1, qf[d8], sc1, 0, 0, 0);
        }

        float tmax = -INFINITY;
        int last = (kb == nkb - 1);
        #pragma unroll
        for (int r = 0; r < 16; r++) {
            int kl = (r & 3) + 8 * (r >> 2) + 4 * h2;
            float s0 = sc0[r] * inv + slope * (float)(k0 + kl);
            float s1 = sc1[r] * inv + slope * (float)(k0 + 32 + kl);
            if (last) {
                if (k0 + kl > qg) s0 = -INFINITY;
                if (k0 + 32 + kl > qg) s1 = -INFINITY;
            }
            sc0[r] = s0; sc1[r] = s1;
            tmax = fmaxf(tmax, fmaxf(s0, s1));
        }
        tmax = fmaxf(tmax, __shfl_xor(tmax, 32));
        if (!__all(tmax <= m + 8.f)) {          // defer-max (T13)
            float mnew = fmaxf(m, tmax);
            float sca = __expf(m - mnew);
            m = mnew;
            lsum *= sca;
            #pragma unroll
            for (int db = 0; db < 4; db++)
                #pragma unroll
                for (int e = 0; e < 16; e++) ao[db][e] *= sca;
        }
        float psum = 0.f;
        #pragma unroll
        for (int r = 0; r < 16; r++) {
            sc0[r] = __expf(sc0[r] - m); psum += sc0[r];
            sc1[r] = __expf(sc1[r] - m); psum += sc1[r];
        }
        psum += __shfl_xor(psum, 32);
        lsum += psum;

        #pragma unroll
        for (int kstep = 0; kstep < 4; kstep++) {
            const int ks1 = kstep & 1;
            float a0, a1, a2, a3, b0, b1, b2, b3;
            if (kstep < 2) {
                a0 = sc0[8*ks1+0]; a1 = sc0[8*ks1+1]; a2 = sc0[8*ks1+2]; a3 = sc0[8*ks1+3];
                b0 = sc0[8*ks1+4]; b1 = sc0[8*ks1+5]; b2 = sc0[8*ks1+6]; b3 = sc0[8*ks1+7];
            } else {
                a0 = sc1[8*ks1+0]; a1 = sc1[8*ks1+1]; a2 = sc1[8*ks1+2]; a3 = sc1[8*ks1+3];
                b0 = sc1[8*ks1+4]; b1 = sc1[8*ks1+5]; b2 = sc1[8*ks1+6]; b3 = sc1[8*ks1+7];
            }
            unsigned ku0 = pack_bf2(h2 ? b0 : a0, h2 ? b1 : a1);
            unsigned ku1 = pack_bf2(h2 ? b2 : a2, h2 ? b3 : a3);
            unsigned su0 = pack_bf2(h2 ? a0 : b0, h2 ? a1 : b1);
            unsigned su1 = pack_bf2(h2 ? a2 : b2, h2 ? a3 : b3);
            unsigned r0 = (unsigned)__shfl_xor((int)su0, 32);
            unsigned r1 = (unsigned)__shfl_xor((int)su1, 32);
            union { int4 i; bf16x8 v; } u;
            u.i.x = h2 ? (int)r0  : (int)ku0;
            u.i.y = h2 ? (int)r1  : (int)ku1;
            u.i.z = h2 ? (int)ku0 : (int)r0;
            u.i.w = h2 ? (int)ku1 : (int)r1;
            bf16x8 pf = u.v;
            int ch = ((kstep * 2 + h2) ^ (l32 & 7)) << 4;
            #pragma unroll
            for (int db = 0; db < 4; db++) {
                bf16x8 vf = *(const bf16x8*)(vsb + (db * 32 + l32) * 128 + ch);
                ao[db] = __builtin_amdgcn_mfma_f32_32x32x16_bf16(vf, pf, ao[db], 0, 0, 0);
            }
        }
    }

    float rl = 1.f / lsum;
    #pragma unroll
    for (int db = 0; db < 4; db++)
        #pragma unroll
        for (int g = 0; g < 4; g++) {
            ushort4 o;
            o.x = f2bf(ao[db][g*4+0] * rl);
            o.y = f2bf(ao[db][g*4+1] * rl);
            o.z = f2bf(ao[db][g*4+2] * rl);
            o.w = f2bf(ao[db][g*4+3] * rl);
            *(ushort4*)(ctx + (size_t)qg * HH + n * HD + db * 32 + g * 8 + h2 * 4) = o;
        }
}

extern "C" void kernel_launch(void* const* d_in, const int* in_sizes, int n_in,
                              void* d_out, int out_size, void* d_ws, size_t ws_size,
                              hipStream_t stream) {
    const float* hs    = (const float*)d_in[0];
    const float* ln1g  = (const float*)d_in[4];
    const float* ln1b  = (const float*)d_in[5];
    const float* qkvw  = (const float*)d_in[6];
    const float* qkvb  = (const float*)d_in[7];
    const float* dw    = (const float*)d_in[8];
    const float* db    = (const float*)d_in[9];
    const float* ln2g  = (const float*)d_in[10];
    const float* ln2b  = (const float*)d_in[11];
    const float* f1w   = (const float*)d_in[12];
    const float* f1b   = (const float*)d_in[13];
    const float* f2w   = (const float*)d_in[14];
    const float* f2b   = (const float*)d_in[15];
    float* out = (float*)d_out;

    char* ws = (char*)d_ws;
    size_t off = 0;
    auto alloc = [&](size_t nbytes) {
        void* p = ws + off; off += (nbytes + 255) & ~(size_t)255; return p;
    };
    unsigned short* xbf  = (unsigned short*)alloc((size_t)SQ * HH * 2);        // [0, 8.39M)
    unsigned short* qkvB = (unsigned short*)alloc((size_t)SQ * QKVW * 2);      // [8.39M, 33.55M)
    unsigned short* vtB  = (unsigned short*)alloc((size_t)NHEAD * HD * SQ * 2);// [33.55M, 41.94M)
    unsigned short* ctx  = (unsigned short*)alloc((size_t)SQ * HH * 2);        // [41.94M, 50.33M)
    float*          attn = (float*)alloc((size_t)SQ * HH * 4);                 // [50.33M, 67.11M)
    unsigned short* y    = (unsigned short*)alloc((size_t)SQ * HH * 2);        // [67.11M, 75.50M)
    unsigned short* hdn  = (unsigned short*)alloc((size_t)SQ * 4 * HH * 2);    // [75.50M, 109.05M)
    unsigned short* wbuf = (unsigned short*)alloc((size_t)4 * HH * HH * 2);    // [109.05M, 142.61M)

    const size_t PQ = (size_t)SQ * HH;      // floats per partial (16.78 MB)
    float* part = (float*)ws;               // partials overlap dead early buffers

    ln_kernel<<<SQ, 256, 0, stream>>>(hs, ln1g, ln1b, xbf);

    // QKV: M=2048,N=6144,K=2048. grid 24x8 = 192 blocks; CH=4,CW=6 (cgx=4).
    cvt_kernel<<<2048, 256, 0, stream>>>(qkvw, wbuf, QKVW * HH / 4);
    gemm1024<2, 0><<<dim3(QKVW / 256, SQ / 256, 1), 1024, 0, stream>>>(
        xbf, wbuf, qkvb, qkvB, vtB, nullptr, nullptr, QKVW, HH, HH, HH, HH, 4, 6);

    attn_kernel<<<512, 128, 0, stream>>>(qkvB, vtB, ctx);

    // dense: split-K x4 (8x8x4 = 256 blocks, kLen=512, nt=8); CH=8,CW=4 (cgx=2).
    // partials: p0,p1 at ws[0,33.55M) (dead xbf+qkvB); p2,p3 in dead hdn.
    cvt_kernel<<<1024, 256, 0, stream>>>(dw, wbuf, HH * HH / 4);
    gemm1024<0, 0><<<dim3(HH / 256, SQ / 256, 4), 1024, 0, stream>>>(
        ctx, wbuf, nullptr, part, nullptr, hdn, (float*)hdn + PQ,
        HH, HH, HH, HH / 4, HH, 8, 4);
    reduceN_kernel<4><<<2048, 256, 0, stream>>>(
        part, part + PQ, (float*)hdn, (float*)hdn + PQ, hs, db, attn, SQ * HH / 4, HH / 4 - 1);

    ln_kernel<<<SQ, 256, 0, stream>>>(attn, ln2g, ln2b, y);

    // FC1: M=2048,N=8192,K=2048. grid 32x8 = 256 blocks; CH=4,CW=8 (cgx=4).
    cvt_kernel<<<2048, 256, 0, stream>>>(f1w, wbuf, 4 * HH * HH / 4);
    gemm1024<1, 1><<<dim3(4 * HH / 256, SQ / 256, 1), 1024, 0, stream>>>(
        y, wbuf, f1b, hdn, nullptr, nullptr, nullptr, 4 * HH, HH, HH, HH, HH, 4, 8);

    // FC2: split-K x4 (8x8x4 = 256 blocks, kLen=2048, nt=32); CH=8,CW=4.
    // partials p0,p1,p2 at ws[0,50.33M) (dead xbf+qkvB+vtB+ctx); p3 = out.
    cvt_kernel<<<2048, 256, 0, stream>>>(f2w, wbuf, 4 * HH * HH / 4);
    gemm1024<0, 0><<<dim3(HH / 256, SQ / 256, 4), 1024, 0, stream>>>(
        hdn, wbuf, nullptr, part, nullptr, part + 2 * PQ, out,
        HH, 4 * HH, 4 * HH, HH, 4 * HH, 8, 4);
    reduceN_kernel<4><<<2048, 256, 0, stream>>>(
        part, part + PQ, part + 2 * PQ, out, attn, f2b, out, SQ * HH / 4, HH / 4 - 1);
}